// Round 1
// 119.222 us; speedup vs baseline: 1.0114x; 1.0114x over previous
//
#include <hip/hip_runtime.h>
#include <hip/hip_fp16.h>

typedef _Float16 f16;
typedef _Float16 f16x8 __attribute__((ext_vector_type(8)));
typedef float f32x4 __attribute__((ext_vector_type(4)));

__device__ __forceinline__ f16x8 relu8(f16x8 a) {
#if __has_builtin(__builtin_elementwise_max)
  return __builtin_elementwise_max(a, (f16x8)(f16)0);   // v_pk_max_f16 x4
#else
  f16x8 r;
#pragma unroll
  for (int i = 0; i < 8; i++) r[i] = a[i] > (f16)0 ? a[i] : (f16)0;
  return r;
#endif
}

__device__ __forceinline__ f16x8 bcast8(f16 s) {
  return (f16x8){s, s, s, s, s, s, s, s};
}

// ---------------------------------------------------------------------------
// fused (R19 final, unchanged this round except: C-zeroing removed — the new
// k_atta2 overwrites every element of C directly, so no pre-zero is needed).
// 256 persistent blocks, 512 thr = 8 waves, 1 block/CU.
// Structural optimum after 20 rounds:
// - 16x16x32 MFMA, wave tile rg=8 x cg=4 (acc 128 AGPR). 32x32 regressed
//   (R15: more LDS reads/K, longer phase-lock chains).
// - 2 waves/SIMD is the register-file optimum: acc 128 AGPR + ~110 VGPR
//   working set = 240/256. All >2-wave or prefetch attempts spilled
//   (R10/R12/R18/R20 — WRITE_SIZE canary 9-34 MB each time).
// - W2 nh-slice (128 KB) LDS-resident, gathered directly from global on nh
//   change; A-fragments regenerated in registers (relu(xj*w1b + xi*w1a+b1)).
// - R14 balanced task map: 128 cheap diagonal tasks paired complementary in
//   {0..63,256..319}; 192 full tasks in {64..255}; max load 1.06 full-equiv.
// WRITE_SIZE ~1.0 MB = no-spill canary.
// ---------------------------------------------------------------------------
__global__ __launch_bounds__(512, 2) void k_fused(
    const float* __restrict__ x, const float* __restrict__ W1,
    const float* __restrict__ b1, const float* __restrict__ b2,
    const float* __restrict__ W3, const float* __restrict__ b3,
    const float* __restrict__ W2,
    float* __restrict__ Kp0, float* __restrict__ Kp1) {
  __shared__ f16 w2f[65536];                 // 128 KB: current nh's B-fragments
  __shared__ f16 w1af[1024], b1f[1024], w1bf[1024];
  __shared__ f16 hat[8192];                  // 16 KB: ha rows for task's 8 i
  __shared__ f16 xs[512];                    // f16(x)

  const int tid = threadIdx.x;
  const int lane = tid & 63, wv = tid >> 6;
  const int cL = lane & 15, q = lane >> 4;

  // --- one-time staging: W1 tables + f16(x)
  if (tid < 128) {
    const int c8 = tid << 3;
    const float4 a0 = *(const float4*)(W1 + c8);
    const float4 a1 = *(const float4*)(W1 + c8 + 4);
    const float4 g0 = *(const float4*)(b1 + c8);
    const float4 g1 = *(const float4*)(b1 + c8 + 4);
    f16x8 oa, og;
    oa[0] = (f16)a0.x; oa[1] = (f16)a0.y; oa[2] = (f16)a0.z; oa[3] = (f16)a0.w;
    oa[4] = (f16)a1.x; oa[5] = (f16)a1.y; oa[6] = (f16)a1.z; oa[7] = (f16)a1.w;
    og[0] = (f16)g0.x; og[1] = (f16)g0.y; og[2] = (f16)g0.z; og[3] = (f16)g0.w;
    og[4] = (f16)g1.x; og[5] = (f16)g1.y; og[6] = (f16)g1.z; og[7] = (f16)g1.w;
    *(f16x8*)(&w1af[c8]) = oa;
    *(f16x8*)(&b1f[c8]) = og;
  } else if (tid < 256) {
    const int c8 = (tid - 128) << 3;
    const float4 a0 = *(const float4*)(W1 + 1024 + c8);
    const float4 a1 = *(const float4*)(W1 + 1024 + c8 + 4);
    f16x8 ob;
    ob[0] = (f16)a0.x; ob[1] = (f16)a0.y; ob[2] = (f16)a0.z; ob[3] = (f16)a0.w;
    ob[4] = (f16)a1.x; ob[5] = (f16)a1.y; ob[6] = (f16)a1.z; ob[7] = (f16)a1.w;
    *(f16x8*)(&w1bf[c8]) = ob;
  } else if (tid < 320) {
    const int c8 = (tid - 256) << 3;
    const float4 x0 = *(const float4*)(x + c8);
    const float4 x1 = *(const float4*)(x + c8 + 4);
    f16x8 ox;
    ox[0] = (f16)x0.x; ox[1] = (f16)x0.y; ox[2] = (f16)x0.z; ox[3] = (f16)x0.w;
    ox[4] = (f16)x1.x; ox[5] = (f16)x1.y; ox[6] = (f16)x1.z; ox[7] = (f16)x1.w;
    *(f16x8*)(&xs[c8]) = ox;
  }

  int cur_nh = -1;

  for (int t = (int)blockIdx.x; t < 320; t += 256) {
    // --- task map (R14): cheap diagonal in {0..63, 256..319}, full in {64..255}
    int nh, jt, s;
    if (t < 64 || t >= 256) {
      const int b = (t < 64) ? t : (t - 256);
      nh = b & 1;
      const int jd = b >> 1;              // 0..31
      const int jt1 = jd >> 4, l = jd & 15;
      if (t < 64) { jt = jt1;            s = jt * 16 + l; }
      else        { jt = (jt1 + 2) & 3;  s = jt * 16 + (15 - l); }
    } else {
      const int f = t - 64;               // 0..191
      nh = f & 1;
      const int jf = f >> 1;              // 0..95
      if (jf < 16)      { jt = 1; s = jf; }
      else if (jf < 48) { jt = 2; s = jf - 16; }
      else              { jt = 3; s = jf - 48; }
    }
    const int i0 = s << 3, j0 = jt << 7;
    float* __restrict__ Kp = nh ? Kp1 : Kp0;

    __syncthreads();                  // prior task's LDS reads done; covers one-time staging
    if (nh != cur_nh) {               // gather this nh's W2 fragments from GLOBAL
      #pragma unroll
      for (int p = 0; p < 16; p++) {
        const int sl = p * 512 + tid;           // slot 0..8191
        const int frag = sl >> 6, l = sl & 63;
        const int cgL = frag >> 5, kb2 = frag & 31;
        const int q2 = l >> 4, cL2 = l & 15;
        const int n = nh * 64 + cgL * 16 + cL2;
        const float* src = W2 + (kb2 * 32 + q2 * 8) * 128 + n;
        f16x8 o;
        #pragma unroll
        for (int e = 0; e < 8; e++) o[e] = (f16)src[e * 128];
        *(f16x8*)(&w2f[frag * 512 + l * 8]) = o;
      }
      cur_nh = nh;
    }
    {  // hat[il][k] = f16(x[i0+il]*W1a[k] + b1[k]); 512 thr x 16 f16
      const int il_s = tid >> 6, kb = (tid & 63) << 4;
      const f16x8 xv = bcast8(xs[i0 + il_s]);
      const f16x8 wa0 = *(const f16x8*)(&w1af[kb]);
      const f16x8 wa1 = *(const f16x8*)(&w1af[kb + 8]);
      const f16x8 bb0 = *(const f16x8*)(&b1f[kb]);
      const f16x8 bb1 = *(const f16x8*)(&b1f[kb + 8]);
      *(f16x8*)(&hat[il_s * 1024 + kb])     = xv * wa0 + bb0;
      *(f16x8*)(&hat[il_s * 1024 + kb + 8]) = xv * wa1 + bb1;
    }
    __syncthreads();

    const int i = i0 + wv;
    const int dij = i - j0;
    const int rgmin = (dij > 0) ? (dij >> 4) : 0;   // wave-uniform skip

    f16 xjs[8];
    #pragma unroll
    for (int rg = 0; rg < 8; rg++) xjs[rg] = xs[j0 + rg * 16 + cL];

    f32x4 acc[8][4];
    #pragma unroll
    for (int rg = 0; rg < 8; rg++)
      #pragma unroll
      for (int cg = 0; cg < 4; cg++) acc[rg][cg] = (f32x4){0.f, 0.f, 0.f, 0.f};

    const f16* hrow  = hat + wv * 1024 + q * 8;
    const f16* wrow  = w1bf + q * 8;
    const f16* bbase = w2f + lane * 8;

    for (int kk = 0; kk < 32; ++kk) {
      const f16x8 hv = *(const f16x8*)(hrow + kk * 32);
      const f16x8 wb = *(const f16x8*)(wrow + kk * 32);
      f16x8 bf[4];
      #pragma unroll
      for (int cg = 0; cg < 4; cg++)
        bf[cg] = *(const f16x8*)(bbase + (cg * 32 + kk) * 512);
      #pragma unroll
      for (int rg = 0; rg < 8; rg++) {
        if (rg >= rgmin) {
          const f16x8 af = relu8(bcast8(xjs[rg]) * wb + hv);
          #pragma unroll
          for (int cg = 0; cg < 4; cg++)
            acc[rg][cg] = __builtin_amdgcn_mfma_f32_16x16x32_f16(af, bf[cg], acc[rg][cg], 0, 0, 0);
        }
      }
    }

    // --- epilogue: dot over this nh's 64 n; direct global writes (1 i/wave)
    float b2v[4], w3v[4];
    #pragma unroll
    for (int cg = 0; cg < 4; cg++) {
      b2v[cg] = b2[nh * 64 + cg * 16 + cL];
      w3v[cg] = W3[nh * 64 + cg * 16 + cL];
    }
    const float badd = (nh == 0) ? b3[0] : 0.f;   // b3 added exactly once
    #pragma unroll
    for (int rg = 0; rg < 8; rg++) {
      if (rg >= rgmin) {
        #pragma unroll
        for (int r = 0; r < 4; r++) {
          float ssum = 0.f;
          #pragma unroll
          for (int cg = 0; cg < 4; cg++)
            ssum = fmaf(fmaxf(acc[rg][cg][r] + b2v[cg], 0.f), w3v[cg], ssum);
          ssum += __shfl_xor(ssum, 1, 64);
          ssum += __shfl_xor(ssum, 2, 64);
          ssum += __shfl_xor(ssum, 4, 64);
          ssum += __shfl_xor(ssum, 8, 64);
          if (cL == 0) {
            const int j = j0 + rg * 16 + q * 4 + r;  // C row = q*4 + reg
            if (j >= i) Kp[i * 512 + j] = ssum + badd;
          }
        }
      }
    }
  }
}

// ---------------------------------------------------------------------------
// atta2 (R21 rewrite): tile-ownership KtK, NO ATOMICS.
// Old split-K scheme issued ~1.34M global atomic_add_f32 RMWs (816 blocks x
// 256 thr x ~6.5) — atomic serialization at L2 was the ~40 us tail.
// New: one block per chunk-pair (a<=b) = 136 blocks. Block owns the 32x32
// tile C[pb:pb+32, qb:qb+32] and its mirror; loops its own i-chunks
// (K[i,p] == 0 for i > p, so reduction depth = a+1 chunks, max 16).
// Ping-pong LDS (one __syncthreads per chunk), next chunk's global loads
// issued under the FMA loop, triu-mask applied at LDS-store time (Kp lower
// triangle is uninitialized workspace). Direct float2 stores of tile +
// transposed mirror fully overwrite C — no pre-zero needed anywhere.
// ---------------------------------------------------------------------------
__global__ __launch_bounds__(256) void k_atta2(const float* __restrict__ K0,
                                               const float* __restrict__ K1,
                                               float* __restrict__ C) {
  __shared__ __align__(16) float sp[2][32 * 36];
  __shared__ __align__(16) float sq[2][32 * 36];

  int a = 0, rem = (int)blockIdx.x;
  #pragma unroll
  for (int aa = 0; aa < 16; aa++) {
    const int c = 16 - aa;
    if (rem < c) { a = aa; break; }
    rem -= c;
  }
  const int b = a + rem;
  const int pb = a * 32, qb = b * 32;
  const int nchunk = a + 1;               // K[i,p]=0 for i>p  =>  i < (a+1)*32

  const int tid = threadIdx.x;
  const int ii = tid >> 3, p4 = (tid & 7) << 2;   // loader: 32 rows x 8 quads
  const int tx = tid & 15, ty = tid >> 4;         // compute: 16x16, 2x2 micro

  // prefetch chunk 0
  float4 x0, x1, y0, y1;
  {
    const int gp = ii * 512 + pb + p4, gq = ii * 512 + qb + p4;
    x0 = *(const float4*)(K0 + gp);
    x1 = *(const float4*)(K1 + gp);
    y0 = *(const float4*)(K0 + gq);
    y1 = *(const float4*)(K1 + gq);
  }

  float c00 = 0.f, c01 = 0.f, c10 = 0.f, c11 = 0.f;

  for (int ic = 0; ic < nchunk; ic++) {
    float* __restrict__ spb = sp[ic & 1];
    float* __restrict__ sqb = sq[ic & 1];
    const int r = ic * 32 + ii;
    // triu mask (lower triangle of Kp0/Kp1 is garbage workspace)
    float4 vp, vq;
    vp.x = (r <= pb + p4 + 0) ? x0.x + x1.x : 0.f;
    vp.y = (r <= pb + p4 + 1) ? x0.y + x1.y : 0.f;
    vp.z = (r <= pb + p4 + 2) ? x0.z + x1.z : 0.f;
    vp.w = (r <= pb + p4 + 3) ? x0.w + x1.w : 0.f;
    vq.x = (r <= qb + p4 + 0) ? y0.x + y1.x : 0.f;
    vq.y = (r <= qb + p4 + 1) ? y0.y + y1.y : 0.f;
    vq.z = (r <= qb + p4 + 2) ? y0.z + y1.z : 0.f;
    vq.w = (r <= qb + p4 + 3) ? y0.w + y1.w : 0.f;
    *(float4*)&spb[ii * 36 + p4] = vp;
    *(float4*)&sqb[ii * 36 + p4] = vq;
    __syncthreads();

    if (ic + 1 < nchunk) {   // issue next chunk's loads under the FMA loop
      const int r2 = (ic + 1) * 32 + ii;
      const int gp = r2 * 512 + pb + p4, gq = r2 * 512 + qb + p4;
      x0 = *(const float4*)(K0 + gp);
      x1 = *(const float4*)(K1 + gp);
      y0 = *(const float4*)(K0 + gq);
      y1 = *(const float4*)(K1 + gq);
    }

    #pragma unroll 8
    for (int k = 0; k < 32; k++) {
      const float2 av = *(const float2*)&spb[k * 36 + ty * 2];
      const float2 bv = *(const float2*)&sqb[k * 36 + tx * 2];
      c00 = fmaf(av.x, bv.x, c00); c01 = fmaf(av.x, bv.y, c01);
      c10 = fmaf(av.y, bv.x, c10); c11 = fmaf(av.y, bv.y, c11);
    }
    // next iteration stores to the OTHER buffer; the barrier above (next ic)
    // orders compute(ic) before any thread's store into this buffer (ic+2)
  }

  const int p0 = pb + ty * 2, q0 = qb + tx * 2;
  *(float2*)&C[p0 * 512 + q0]       = make_float2(c00, c01);
  *(float2*)&C[(p0 + 1) * 512 + q0] = make_float2(c10, c11);
  if (pb != qb) {  // mirror tile (C symmetric); diagonal tile already full
    *(float2*)&C[q0 * 512 + p0]       = make_float2(c00, c10);
    *(float2*)&C[(q0 + 1) * 512 + p0] = make_float2(c01, c11);
  }
}

extern "C" void kernel_launch(void* const* d_in, const int* in_sizes, int n_in,
                              void* d_out, int out_size, void* d_ws, size_t ws_size,
                              hipStream_t stream) {
  const float* x  = (const float*)d_in[0];
  const float* W1 = (const float*)d_in[1];
  const float* b1 = (const float*)d_in[2];
  const float* W2 = (const float*)d_in[3];
  const float* b2 = (const float*)d_in[4];
  const float* W3 = (const float*)d_in[5];
  const float* b3 = (const float*)d_in[6];
  float* out = (float*)d_out;
  char* ws = (char*)d_ws;

  float* Kp0 = (float*)ws;                          // 1 MB partial K (n 0..63)
  float* Kp1 = (float*)(ws + (1 << 20));            // 1 MB partial K (n 64..127)

  k_fused<<<256, 512, 0, stream>>>(x, W1, b1, b2, W3, b3, W2, Kp0, Kp1);
  k_atta2<<<136, 256, 0, stream>>>(Kp0, Kp1, out);
}